// Round 1
// baseline (3810.133 us; speedup 1.0000x reference)
//
#include <hip/hip_runtime.h>
#include <hip/hip_bf16.h>

#define N_NODES 100000
#define D 128
#define N_REL 4
#define N_EDGES 500000

static constexpr size_t BUF_ELEMS  = (size_t)N_REL * N_NODES * D;   // 51,200,000 floats
static constexpr size_t DEG_ELEMS  = (size_t)N_REL * N_NODES;       // 400,000 floats
static constexpr size_t BMAT_ELEMS = 640 * 128;                     // 81,920 floats

// Build B matrix [640][128]: B[k][f] = W[r][f][d] for k=r*128+d (k<512), W_sl[f][k-512] else.
__global__ __launch_bounds__(256) void build_bmat(const float* __restrict__ W,
                                                  const float* __restrict__ W_sl,
                                                  float* __restrict__ Bmat) {
    int t = blockIdx.x * 256 + threadIdx.x;
    if (t >= 640 * 128) return;
    int k = t >> 7, f = t & 127;
    float v;
    if (k < 512) {
        int r = k >> 7, d = k & 127;
        v = W[((size_t)r * 128 + f) * 128 + d];
    } else {
        v = W_sl[(size_t)f * 128 + (k - 512)];
    }
    Bmat[t] = v;
}

// Scatter: 32 lanes per edge; each lane gathers a float4 of x[src] and atomically
// adds into buf[r][tgt]. Lane 0 bumps the degree counter.
__global__ __launch_bounds__(256) void scatter_kernel(const float* __restrict__ x,
                                                      const int* __restrict__ ei,
                                                      float* __restrict__ buf,
                                                      float* __restrict__ deg) {
    long long gid = (long long)blockIdx.x * 256 + threadIdx.x;
    int team = (int)(gid >> 5);
    int lane = (int)(gid & 31);
    if (team >= N_REL * N_EDGES) return;
    int r = team / N_EDGES;
    int e = team - r * N_EDGES;
    const int* eiR = ei + (size_t)r * 2 * N_EDGES;
    int src = eiR[e];
    int tgt = eiR[N_EDGES + e];
    float4 v = ((const float4*)(x + (size_t)src * D))[lane];
    float* dst = buf + ((size_t)r * N_NODES + tgt) * D + lane * 4;
    unsafeAtomicAdd(dst + 0, v.x);
    unsafeAtomicAdd(dst + 1, v.y);
    unsafeAtomicAdd(dst + 2, v.z);
    unsafeAtomicAdd(dst + 3, v.w);
    if (lane == 0) unsafeAtomicAdd(&deg[(size_t)r * N_NODES + tgt], 1.0f);
}

// C[100000][128] = A[100000][640] * B[640][128] + bias epilogue.
// A columns: k in [0,512) -> buf[r=k/128][n][k%128]; k in [512,640) -> x[n][k-512].
__global__ __launch_bounds__(256) void gemm_kernel(const float* __restrict__ buf,
                                                   const float* __restrict__ x,
                                                   const float* __restrict__ Bmat,
                                                   const float* __restrict__ deg,
                                                   const float* __restrict__ bias,
                                                   const float* __restrict__ b_sl,
                                                   float* __restrict__ out) {
    __shared__ __align__(16) float As[64 * 65];    // [row][k], stride 65 (scalar access only)
    __shared__ __align__(16) float Bs[64 * 128];   // [k][f]
    __shared__ float degS[4 * 64];
    __shared__ float biasS[4 * 128];
    __shared__ float bslS[128];

    const int tid = threadIdx.x;
    const int tx = tid & 15;   // 16 -> covers 128 cols as tx*4 + {0..3} + jj*64
    const int ty = tid >> 4;   // 16 -> covers 64 rows as ty*4 + {0..3}
    const int row0 = blockIdx.x * 64;

    if (tid < 128) bslS[tid] = b_sl[tid];
    biasS[tid] = bias[tid];
    biasS[256 + tid] = bias[256 + tid];
    {
        int r = tid >> 6;
        int rr = tid & 63;
        int n = row0 + rr;
        degS[tid] = (n < N_NODES) ? deg[(size_t)r * N_NODES + n] : 0.0f;
    }

    float acc[4][8];
#pragma unroll
    for (int i = 0; i < 4; ++i)
#pragma unroll
        for (int j = 0; j < 8; ++j) acc[i][j] = 0.0f;

    for (int kt = 0; kt < 10; ++kt) {
        __syncthreads();  // protect LDS from previous iteration's readers
        const int region = kt >> 1;
        const int d0 = (kt & 1) * 64;
        // Load A tile 64 rows x 64 k (transposed-scalar store; 2-way bank alias = free)
#pragma unroll
        for (int p = 0; p < 4; ++p) {
            int row = p * 16 + ty;
            int n = row0 + row;
            float4 v = make_float4(0.f, 0.f, 0.f, 0.f);
            if (n < N_NODES) {
                const float* sp = (region < 4)
                    ? (buf + ((size_t)region * N_NODES + n) * D + d0)
                    : (x + (size_t)n * D + d0);
                v = *(const float4*)(sp + tx * 4);
            }
            int c = tx * 4;
            As[row * 65 + c + 0] = v.x;
            As[row * 65 + c + 1] = v.y;
            As[row * 65 + c + 2] = v.z;
            As[row * 65 + c + 3] = v.w;
        }
        // Load B tile 64 k x 128 f (coalesced float4)
#pragma unroll
        for (int p = 0; p < 8; ++p) {
            int idx = p * 256 + tid;
            int kd = idx >> 5;
            int f4 = idx & 31;
            float4 v = ((const float4*)(Bmat + ((size_t)kt * 64 + kd) * 128))[f4];
            *(float4*)&Bs[kd * 128 + f4 * 4] = v;
        }
        __syncthreads();
#pragma unroll 2
        for (int k = 0; k < 64; ++k) {
            float a[4];
            a[0] = As[(ty * 4 + 0) * 65 + k];
            a[1] = As[(ty * 4 + 1) * 65 + k];
            a[2] = As[(ty * 4 + 2) * 65 + k];
            a[3] = As[(ty * 4 + 3) * 65 + k];
            const float4 b0 = *(const float4*)&Bs[k * 128 + tx * 4];
            const float4 b1 = *(const float4*)&Bs[k * 128 + 64 + tx * 4];
            float bv[8] = {b0.x, b0.y, b0.z, b0.w, b1.x, b1.y, b1.z, b1.w};
#pragma unroll
            for (int i = 0; i < 4; ++i)
#pragma unroll
                for (int j = 0; j < 8; ++j)
                    acc[i][j] = fmaf(a[i], bv[j], acc[i][j]);
        }
    }

    // Epilogue: + sum_r deg[r][n]*b[r][f] + b_sl[f]
#pragma unroll
    for (int i = 0; i < 4; ++i) {
        int row = ty * 4 + i;
        int n = row0 + row;
        if (n >= N_NODES) continue;
        float dg0 = degS[0 * 64 + row];
        float dg1 = degS[1 * 64 + row];
        float dg2 = degS[2 * 64 + row];
        float dg3 = degS[3 * 64 + row];
#pragma unroll
        for (int jj = 0; jj < 2; ++jj) {
            int c = jj * 64 + tx * 4;
            float4 o;
            float* accp = &acc[i][jj * 4];
            o.x = accp[0] + dg0 * biasS[c + 0] + dg1 * biasS[128 + c + 0] + dg2 * biasS[256 + c + 0] + dg3 * biasS[384 + c + 0] + bslS[c + 0];
            o.y = accp[1] + dg0 * biasS[c + 1] + dg1 * biasS[128 + c + 1] + dg2 * biasS[256 + c + 1] + dg3 * biasS[384 + c + 1] + bslS[c + 1];
            o.z = accp[2] + dg0 * biasS[c + 2] + dg1 * biasS[128 + c + 2] + dg2 * biasS[256 + c + 2] + dg3 * biasS[384 + c + 2] + bslS[c + 2];
            o.w = accp[3] + dg0 * biasS[c + 3] + dg1 * biasS[128 + c + 3] + dg2 * biasS[256 + c + 3] + dg3 * biasS[384 + c + 3] + bslS[c + 3];
            *(float4*)(out + (size_t)n * 128 + c) = o;
        }
    }
}

extern "C" void kernel_launch(void* const* d_in, const int* in_sizes, int n_in,
                              void* d_out, int out_size, void* d_ws, size_t ws_size,
                              hipStream_t stream) {
    const float* x    = (const float*)d_in[0];
    const int*   ei   = (const int*)d_in[1];
    const float* W    = (const float*)d_in[2];
    const float* b    = (const float*)d_in[3];
    const float* W_sl = (const float*)d_in[4];
    const float* b_sl = (const float*)d_in[5];
    float* out = (float*)d_out;

    float* buf  = (float*)d_ws;
    float* deg  = buf + BUF_ELEMS;
    float* Bmat = deg + DEG_ELEMS;

    // Zero accumulation buffers (harness poisons d_ws with 0xAA each call)
    hipMemsetAsync(d_ws, 0, (BUF_ELEMS + DEG_ELEMS) * sizeof(float), stream);

    build_bmat<<<(640 * 128 + 255) / 256, 256, 0, stream>>>(W, W_sl, Bmat);

    // 32 lanes per edge, 8 edges per 256-thread block
    long long teams = (long long)N_REL * N_EDGES;           // 2,000,000
    long long threads = teams * 32;                          // 64,000,000
    int blocks = (int)((threads + 255) / 256);               // 250,000
    scatter_kernel<<<blocks, 256, 0, stream>>>(x, ei, buf, deg);

    gemm_kernel<<<(N_NODES + 63) / 64, 256, 0, stream>>>(buf, x, Bmat, deg, b, b_sl, out);
}

// Round 2
// 2204.830 us; speedup vs baseline: 1.7281x; 1.7281x over previous
//
#include <hip/hip_runtime.h>
#include <hip/hip_bf16.h>

#define N_NODES 100000
#define D 128
#define N_REL 4
#define N_EDGES 500000
#define NODES_PER_BLK 64
#define N_BLK ((N_NODES + NODES_PER_BLK - 1) / NODES_PER_BLK)   // 1563
#define N_BUCKET (N_REL * N_BLK)                                 // 6252
#define AS_STRIDE 130   // pad 128->130: column reads land on 4 distinct banks (conflict-free broadcast); even => float2-aligned

// ---------------- B matrix: [640][128], B[k][f] = W[r][f][d] (k=r*128+d, k<512) else W_sl[f][k-512]
__global__ __launch_bounds__(256) void build_bmat(const float* __restrict__ W,
                                                  const float* __restrict__ W_sl,
                                                  float* __restrict__ Bmat) {
    int t = blockIdx.x * 256 + threadIdx.x;
    if (t >= 640 * 128) return;
    int k = t >> 7, f = t & 127;
    float v;
    if (k < 512) {
        int r = k >> 7, d = k & 127;
        v = W[((size_t)r * 128 + f) * 128 + d];
    } else {
        v = W_sl[(size_t)f * 128 + (k - 512)];
    }
    Bmat[t] = v;
}

// ---------------- Histogram by (relation, tgt>>6): 6252 hot counters in L2
__global__ __launch_bounds__(256) void hist_kernel(const int* __restrict__ ei,
                                                   int* __restrict__ cnt) {
    int t = blockIdx.x * 256 + threadIdx.x;
    if (t >= N_REL * N_EDGES) return;
    int r = t / N_EDGES;
    int e = t - r * N_EDGES;
    int tgt = ei[(size_t)r * 2 * N_EDGES + N_EDGES + e];
    atomicAdd(&cnt[r * N_BLK + (tgt >> 6)], 1);
}

// ---------------- Exclusive scan over 6252 counters (1 block)
__global__ __launch_bounds__(256) void scan_kernel(const int* __restrict__ cnt,
                                                   int* __restrict__ off,
                                                   int* __restrict__ cur) {
    __shared__ int ps[256];
    int t = threadIdx.x;
    int lo = t * 25, hi = lo + 25;
    if (hi > N_BUCKET) hi = N_BUCKET;
    int s = 0;
    for (int i = lo; i < hi; ++i) s += cnt[i];
    ps[t] = s;
    __syncthreads();
    for (int d = 1; d < 256; d <<= 1) {
        int v = (t >= d) ? ps[t - d] : 0;
        __syncthreads();
        ps[t] += v;
        __syncthreads();
    }
    int base = (t == 0) ? 0 : ps[t - 1];
    for (int i = lo; i < hi; ++i) {
        off[i] = base;
        cur[i] = base;
        base += cnt[i];
    }
}

// ---------------- Scatter edges into buckets (returning int atomics, ~320/bucket)
__global__ __launch_bounds__(256) void bucket_kernel(const int* __restrict__ ei,
                                                     int* __restrict__ cur,
                                                     int2* __restrict__ sorted) {
    int t = blockIdx.x * 256 + threadIdx.x;
    if (t >= N_REL * N_EDGES) return;
    int r = t / N_EDGES;
    int e = t - r * N_EDGES;
    int src = ei[(size_t)r * 2 * N_EDGES + e];
    int tgt = ei[(size_t)r * 2 * N_EDGES + N_EDGES + e];
    int pos = atomicAdd(&cur[r * N_BLK + (tgt >> 6)], 1);
    sorted[pos] = make_int2(src, tgt);
}

// ---------------- Fused gather + GEMM + bias. One block = 64 nodes.
// Per relation: build agg tile in LDS via ds_add_f32, then FMA against W_r chunked 32-K at a time.
__global__ __launch_bounds__(256) void fused_kernel(const float* __restrict__ x,
                                                    const int2* __restrict__ sorted,
                                                    const int* __restrict__ off,
                                                    const int* __restrict__ cnt,
                                                    const float* __restrict__ Bmat,
                                                    const float* __restrict__ bias,
                                                    const float* __restrict__ b_sl,
                                                    float* __restrict__ out) {
    __shared__ float As[64 * AS_STRIDE];   // 33.3 KB agg tile [node][d], stride 130
    __shared__ float Bs[32 * 128];         // 16 KB  W chunk [k][f]
    __shared__ float degS[4 * 64];
    __shared__ float biasS[4 * 128];
    __shared__ float bslS[128];

    const int tid  = threadIdx.x;
    const int lane = tid & 63;
    const int wave = tid >> 6;
    const int tx   = tid & 15;   // f: tx*4 + {0..3} + jj*64
    const int ty   = tid >> 4;   // row: ty*4 + {0..3}
    const int n0   = blockIdx.x * 64;

    if (tid < 128) bslS[tid] = b_sl[tid];
    biasS[tid]       = bias[tid];
    biasS[256 + tid] = bias[256 + tid];
    degS[tid]        = 0.0f;

    float acc[4][8];
#pragma unroll
    for (int i = 0; i < 4; ++i)
#pragma unroll
        for (int j = 0; j < 8; ++j) acc[i][j] = 0.0f;

    for (int r = 0; r < 5; ++r) {
        if (r < 4) {
            // zero tile (prev FMA readers already passed the kc-loop trailing barrier)
#pragma unroll
            for (int i = tid; i < 64 * AS_STRIDE; i += 256) As[i] = 0.0f;
            __syncthreads();
            const int b = r * N_BLK + blockIdx.x;
            const int start = off[b];
            const int c = cnt[b];
            // software-pipelined: prefetch next edge record while gathering current
            int2 st = (wave < c) ? sorted[start + wave] : make_int2(0, 0);
            for (int j = wave; j < c; j += 4) {
                int2 e = st;
                if (j + 4 < c) st = sorted[start + j + 4];
                float2 v = ((const float2*)(x + (size_t)e.x * D))[lane];
                int rowb = (e.y & 63) * AS_STRIDE + lane * 2;
                atomicAdd(&As[rowb], v.x);
                atomicAdd(&As[rowb + 1], v.y);
                if (lane == 0) atomicAdd(&degS[r * 64 + (e.y & 63)], 1.0f);
            }
        } else {
            // self-loop: As = x tile (float2 stores: stride 130 is 8B-aligned, not 16B)
#pragma unroll
            for (int i = tid; i < 64 * 64; i += 256) {
                int row = i >> 6, c2 = i & 63;
                int n = n0 + row;
                float2 v = make_float2(0.f, 0.f);
                if (n < N_NODES) v = ((const float2*)(x + (size_t)n * D))[c2];
                *(float2*)&As[row * AS_STRIDE + c2 * 2] = v;
            }
        }
        __syncthreads();   // gather atomics / copy complete

        for (int kc = 0; kc < 4; ++kc) {
            // stage W chunk [32 k][128 f]
#pragma unroll
            for (int p = 0; p < 4; ++p) {
                int u = p * 256 + tid;
                int kd = u >> 5, f4 = u & 31;
                *(float4*)&Bs[kd * 128 + f4 * 4] =
                    ((const float4*)(Bmat + ((size_t)(r * 128 + kc * 32 + kd)) * 128))[f4];
            }
            __syncthreads();
            const int k0 = kc * 32;
#pragma unroll 4
            for (int k = 0; k < 32; ++k) {
                float a0 = As[(ty * 4 + 0) * AS_STRIDE + k0 + k];
                float a1 = As[(ty * 4 + 1) * AS_STRIDE + k0 + k];
                float a2 = As[(ty * 4 + 2) * AS_STRIDE + k0 + k];
                float a3 = As[(ty * 4 + 3) * AS_STRIDE + k0 + k];
                const float4 b0 = *(const float4*)&Bs[k * 128 + tx * 4];
                const float4 b1 = *(const float4*)&Bs[k * 128 + 64 + tx * 4];
                float bv[8] = {b0.x, b0.y, b0.z, b0.w, b1.x, b1.y, b1.z, b1.w};
                float av[4] = {a0, a1, a2, a3};
#pragma unroll
                for (int i = 0; i < 4; ++i)
#pragma unroll
                    for (int j = 0; j < 8; ++j)
                        acc[i][j] = fmaf(av[i], bv[j], acc[i][j]);
            }
            __syncthreads();   // protect Bs (next kc) and As (next relation)
        }
    }

    // epilogue: + sum_r deg[r][n]*b[r][f] + b_sl[f]
#pragma unroll
    for (int i = 0; i < 4; ++i) {
        int row = ty * 4 + i;
        int n = n0 + row;
        if (n >= N_NODES) continue;
        float dg0 = degS[0 * 64 + row];
        float dg1 = degS[1 * 64 + row];
        float dg2 = degS[2 * 64 + row];
        float dg3 = degS[3 * 64 + row];
#pragma unroll
        for (int jj = 0; jj < 2; ++jj) {
            int c = jj * 64 + tx * 4;
            float4 o;
            float* accp = &acc[i][jj * 4];
            o.x = accp[0] + dg0 * biasS[c + 0] + dg1 * biasS[128 + c + 0] + dg2 * biasS[256 + c + 0] + dg3 * biasS[384 + c + 0] + bslS[c + 0];
            o.y = accp[1] + dg0 * biasS[c + 1] + dg1 * biasS[128 + c + 1] + dg2 * biasS[256 + c + 1] + dg3 * biasS[384 + c + 1] + bslS[c + 1];
            o.z = accp[2] + dg0 * biasS[c + 2] + dg1 * biasS[128 + c + 2] + dg2 * biasS[256 + c + 2] + dg3 * biasS[384 + c + 2] + bslS[c + 2];
            o.w = accp[3] + dg0 * biasS[c + 3] + dg1 * biasS[128 + c + 3] + dg2 * biasS[256 + c + 3] + dg3 * biasS[384 + c + 3] + bslS[c + 3];
            *(float4*)(out + (size_t)n * 128 + c) = o;
        }
    }
}

extern "C" void kernel_launch(void* const* d_in, const int* in_sizes, int n_in,
                              void* d_out, int out_size, void* d_ws, size_t ws_size,
                              hipStream_t stream) {
    const float* x    = (const float*)d_in[0];
    const int*   ei   = (const int*)d_in[1];
    const float* W    = (const float*)d_in[2];
    const float* b    = (const float*)d_in[3];
    const float* W_sl = (const float*)d_in[4];
    const float* b_sl = (const float*)d_in[5];
    float* out = (float*)d_out;

    // workspace layout (~16.4 MB total)
    int*   cnt    = (int*)d_ws;
    int*   off    = cnt + N_BUCKET;
    int*   cur    = off + N_BUCKET;
    float* Bmat   = (float*)(cur + N_BUCKET);
    int2*  sorted = (int2*)(Bmat + 640 * 128);

    hipMemsetAsync(cnt, 0, N_BUCKET * sizeof(int), stream);

    build_bmat<<<(640 * 128 + 255) / 256, 256, 0, stream>>>(W, W_sl, Bmat);

    int ethreads = N_REL * N_EDGES;                 // 2,000,000
    int eblocks = (ethreads + 255) / 256;           // 7813
    hist_kernel<<<eblocks, 256, 0, stream>>>(ei, cnt);
    scan_kernel<<<1, 256, 0, stream>>>(cnt, off, cur);
    bucket_kernel<<<eblocks, 256, 0, stream>>>(ei, cur, sorted);

    fused_kernel<<<N_BLK, 256, 0, stream>>>(x, sorted, off, cnt, Bmat, b, b_sl, out);
}

// Round 3
// 816.559 us; speedup vs baseline: 4.6661x; 2.7001x over previous
//
#include <hip/hip_runtime.h>
#include <hip/hip_bf16.h>

#define N_NODES 100000
#define D 128
#define N_REL 4
#define N_EDGES 500000
#define NODES_PER_BLK 64
#define N_BLK ((N_NODES + NODES_PER_BLK - 1) / NODES_PER_BLK)   // 1563
#define N_CNT (N_REL * N_NODES)                                  // 400,000 per-(rel,node) counters
#define SCAN_CHUNK 1024
#define N_SCAN_BLK ((N_CNT + SCAN_CHUNK - 1) / SCAN_CHUNK)       // 391

// ---------------- x -> bf16 copy (rne rounding)
__device__ __forceinline__ unsigned short f2bf_rne(float f) {
    unsigned int u = __float_as_uint(f);
    u += 0x7fffu + ((u >> 16) & 1u);
    return (unsigned short)(u >> 16);
}
__global__ __launch_bounds__(256) void cvt_kernel(const float* __restrict__ x,
                                                  ushort* __restrict__ xbf) {
    int t = blockIdx.x * 256 + threadIdx.x;          // one float4 per thread
    if ((size_t)t * 4 >= (size_t)N_NODES * D) return;
    float4 v = ((const float4*)x)[t];
    ushort4 o;
    o.x = f2bf_rne(v.x); o.y = f2bf_rne(v.y); o.z = f2bf_rne(v.z); o.w = f2bf_rne(v.w);
    ((ushort4*)xbf)[t] = o;
}

// ---------------- B matrix: [640][128], B[k][f] = W[r][f][d] (k=r*128+d, k<512) else W_sl[f][k-512]
__global__ __launch_bounds__(256) void build_bmat(const float* __restrict__ W,
                                                  const float* __restrict__ W_sl,
                                                  float* __restrict__ Bmat) {
    int t = blockIdx.x * 256 + threadIdx.x;
    if (t >= 640 * 128) return;
    int k = t >> 7, f = t & 127;
    float v;
    if (k < 512) {
        int r = k >> 7, d = k & 127;
        v = W[((size_t)r * 128 + f) * 128 + d];
    } else {
        v = W_sl[(size_t)f * 128 + (k - 512)];
    }
    Bmat[t] = v;
}

// ---------------- Histogram per (relation, tgt): 400K counters, L2-hot, avg 5 hits each
__global__ __launch_bounds__(256) void hist_kernel(const int* __restrict__ ei,
                                                   int* __restrict__ cnt) {
    int t = blockIdx.x * 256 + threadIdx.x;
    if (t >= N_REL * N_EDGES) return;
    int r = t / N_EDGES;
    int e = t - r * N_EDGES;
    int tgt = ei[(size_t)r * 2 * N_EDGES + N_EDGES + e];
    atomicAdd(&cnt[r * N_NODES + tgt], 1);
}

// ---------------- 3-kernel exclusive scan over 400K counters
__global__ __launch_bounds__(256) void scanA(const int* __restrict__ cnt,
                                             int* __restrict__ off,
                                             int* __restrict__ partials) {
    __shared__ int ps[256];
    int b = blockIdx.x, t = threadIdx.x;
    int i0 = b * SCAN_CHUNK + t * 4;
    int v[4];
#pragma unroll
    for (int q = 0; q < 4; ++q) v[q] = (i0 + q < N_CNT) ? cnt[i0 + q] : 0;
    int s = v[0] + v[1] + v[2] + v[3];
    ps[t] = s;
    __syncthreads();
    for (int d = 1; d < 256; d <<= 1) {
        int u = (t >= d) ? ps[t - d] : 0;
        __syncthreads();
        ps[t] += u;
        __syncthreads();
    }
    if (t == 255) partials[b] = ps[255];
    int run = (t == 0) ? 0 : ps[t - 1];
#pragma unroll
    for (int q = 0; q < 4; ++q) {
        if (i0 + q < N_CNT) off[i0 + q] = run;
        run += v[q];
    }
}
__global__ __launch_bounds__(512) void scanB(int* __restrict__ partials) {
    __shared__ int ps[512];
    int t = threadIdx.x;
    ps[t] = (t < N_SCAN_BLK) ? partials[t] : 0;
    __syncthreads();
    for (int d = 1; d < 512; d <<= 1) {
        int u = (t >= d) ? ps[t - d] : 0;
        __syncthreads();
        ps[t] += u;
        __syncthreads();
    }
    if (t < N_SCAN_BLK) partials[t] = (t == 0) ? 0 : ps[t - 1];
}
__global__ __launch_bounds__(256) void scanC(int* __restrict__ off,
                                             int* __restrict__ cur,
                                             const int* __restrict__ partials) {
    int i = blockIdx.x * 256 + threadIdx.x;
    if (i >= N_CNT) return;
    int v = off[i] + partials[i >> 10];
    off[i] = v;
    cur[i] = v;
}

// ---------------- Scatter src indices into (rel,tgt)-sorted order
__global__ __launch_bounds__(256) void bucket_kernel(const int* __restrict__ ei,
                                                     int* __restrict__ cur,
                                                     int* __restrict__ sorted) {
    int t = blockIdx.x * 256 + threadIdx.x;
    if (t >= N_REL * N_EDGES) return;
    int r = t / N_EDGES;
    int e = t - r * N_EDGES;
    int src = ei[(size_t)r * 2 * N_EDGES + e];
    int tgt = ei[(size_t)r * 2 * N_EDGES + N_EDGES + e];
    int pos = atomicAdd(&cur[r * N_NODES + tgt], 1);
    sorted[pos] = src;
}

// ---------------- Fused gather + GEMM + bias. One block = 64 nodes, 4 waves.
// Gather: wave owns 16 nodes; per node, register-accumulate bf16 x[src] rows (no atomics),
// one float2 ds_write per node. Then fp32 vector-FMA GEMM against Bmat, per relation.
__global__ __launch_bounds__(256) void fused_kernel(const float* __restrict__ x,
                                                    const ushort* __restrict__ xbf,
                                                    const int* __restrict__ sorted,
                                                    const int* __restrict__ off,
                                                    const int* __restrict__ cnt,
                                                    const float* __restrict__ Bmat,
                                                    const float* __restrict__ bias,
                                                    const float* __restrict__ b_sl,
                                                    float* __restrict__ out) {
    __shared__ __align__(16) float As[64 * 128];   // 32 KB agg tile [node][d]
    __shared__ __align__(16) float Bs[32 * 128];   // 16 KB W chunk [k][f]
    __shared__ float degS[4 * 64];
    __shared__ float biasS[4 * 128];
    __shared__ float bslS[128];

    const int tid  = threadIdx.x;
    const int lane = tid & 63;
    const int wave = tid >> 6;
    const int tx   = tid & 15;   // f: tx*4 + {0..3} + jj*64
    const int ty   = tid >> 4;   // row: ty*4 + {0..3}
    const int n0   = blockIdx.x * 64;

    if (tid < 128) bslS[tid] = b_sl[tid];
    biasS[tid]       = bias[tid];
    biasS[256 + tid] = bias[256 + tid];
    {
        int rel = tid >> 6, row = tid & 63;
        int n = n0 + row;
        degS[tid] = (n < N_NODES) ? (float)cnt[rel * N_NODES + n] : 0.0f;
    }

    float acc[4][8];
#pragma unroll
    for (int i = 0; i < 4; ++i)
#pragma unroll
        for (int j = 0; j < 8; ++j) acc[i][j] = 0.0f;

    for (int r = 0; r < 5; ++r) {
        if (r < 4) {
            // register-accumulated gather, 16 nodes per wave
            const int rbase = r * N_NODES;
#pragma unroll 1
            for (int i = 0; i < 16; ++i) {
                int row = wave * 16 + i;
                int n = n0 + row;
                float ax = 0.0f, ay = 0.0f;
                if (n < N_NODES) {
                    int base = off[rbase + n];
                    int c = cnt[rbase + n];
                    const int byteoff = lane << 1;  // ushort elems; 2 bf16 per lane
                    int j = 0;
                    for (; j + 4 <= c; j += 4) {
                        int s0 = sorted[base + j + 0];
                        int s1 = sorted[base + j + 1];
                        int s2 = sorted[base + j + 2];
                        int s3 = sorted[base + j + 3];
                        unsigned int u0 = *(const unsigned int*)(xbf + ((size_t)s0 << 7) + byteoff);
                        unsigned int u1 = *(const unsigned int*)(xbf + ((size_t)s1 << 7) + byteoff);
                        unsigned int u2 = *(const unsigned int*)(xbf + ((size_t)s2 << 7) + byteoff);
                        unsigned int u3 = *(const unsigned int*)(xbf + ((size_t)s3 << 7) + byteoff);
                        ax += __uint_as_float(u0 << 16) + __uint_as_float(u1 << 16)
                            + __uint_as_float(u2 << 16) + __uint_as_float(u3 << 16);
                        ay += __uint_as_float(u0 & 0xffff0000u) + __uint_as_float(u1 & 0xffff0000u)
                            + __uint_as_float(u2 & 0xffff0000u) + __uint_as_float(u3 & 0xffff0000u);
                    }
                    for (; j < c; ++j) {
                        int s0 = sorted[base + j];
                        unsigned int u0 = *(const unsigned int*)(xbf + ((size_t)s0 << 7) + byteoff);
                        ax += __uint_as_float(u0 << 16);
                        ay += __uint_as_float(u0 & 0xffff0000u);
                    }
                }
                *(float2*)&As[row * 128 + lane * 2] = make_float2(ax, ay);
            }
        } else {
            // self-loop: As = x tile in full fp32
#pragma unroll
            for (int i = tid; i < 64 * 32; i += 256) {
                int row = i >> 5, c4 = i & 31;
                int n = n0 + row;
                float4 v = make_float4(0.f, 0.f, 0.f, 0.f);
                if (n < N_NODES) v = ((const float4*)(x + (size_t)n * D))[c4];
                *(float4*)&As[row * 128 + c4 * 4] = v;
            }
        }
        __syncthreads();   // gather writes visible

        for (int kc = 0; kc < 4; ++kc) {
            // stage W chunk [32 k][128 f]
#pragma unroll
            for (int p = 0; p < 4; ++p) {
                int u = p * 256 + tid;
                int kd = u >> 5, f4 = u & 31;
                *(float4*)&Bs[kd * 128 + f4 * 4] =
                    ((const float4*)(Bmat + ((size_t)(r * 128 + kc * 32 + kd)) * 128))[f4];
            }
            __syncthreads();
            const int k0 = kc * 32;
#pragma unroll 2
            for (int k4 = 0; k4 < 32; k4 += 4) {
                float a_[4][4];
#pragma unroll
                for (int i = 0; i < 4; ++i)
                    *(float4*)a_[i] = *(const float4*)&As[(ty * 4 + i) * 128 + k0 + k4];
#pragma unroll
                for (int kk = 0; kk < 4; ++kk) {
                    const float4 b0 = *(const float4*)&Bs[(k4 + kk) * 128 + tx * 4];
                    const float4 b1 = *(const float4*)&Bs[(k4 + kk) * 128 + 64 + tx * 4];
                    float bv[8] = {b0.x, b0.y, b0.z, b0.w, b1.x, b1.y, b1.z, b1.w};
#pragma unroll
                    for (int i = 0; i < 4; ++i)
#pragma unroll
                        for (int j = 0; j < 8; ++j)
                            acc[i][j] = fmaf(a_[i][kk], bv[j], acc[i][j]);
                }
            }
            __syncthreads();   // protect Bs (next kc) / As (next relation)
        }
    }

    // epilogue: + sum_r deg[r][n]*b[r][f] + b_sl[f]
#pragma unroll
    for (int i = 0; i < 4; ++i) {
        int row = ty * 4 + i;
        int n = n0 + row;
        if (n >= N_NODES) continue;
        float dg0 = degS[0 * 64 + row];
        float dg1 = degS[1 * 64 + row];
        float dg2 = degS[2 * 64 + row];
        float dg3 = degS[3 * 64 + row];
#pragma unroll
        for (int jj = 0; jj < 2; ++jj) {
            int c = jj * 64 + tx * 4;
            float4 o;
            float* accp = &acc[i][jj * 4];
            o.x = accp[0] + dg0 * biasS[c + 0] + dg1 * biasS[128 + c + 0] + dg2 * biasS[256 + c + 0] + dg3 * biasS[384 + c + 0] + bslS[c + 0];
            o.y = accp[1] + dg0 * biasS[c + 1] + dg1 * biasS[128 + c + 1] + dg2 * biasS[256 + c + 1] + dg3 * biasS[384 + c + 1] + bslS[c + 1];
            o.z = accp[2] + dg0 * biasS[c + 2] + dg1 * biasS[128 + c + 2] + dg2 * biasS[256 + c + 2] + dg3 * biasS[384 + c + 2] + bslS[c + 2];
            o.w = accp[3] + dg0 * biasS[c + 3] + dg1 * biasS[128 + c + 3] + dg2 * biasS[256 + c + 3] + dg3 * biasS[384 + c + 3] + bslS[c + 3];
            *(float4*)(out + (size_t)n * 128 + c) = o;
        }
    }
}

extern "C" void kernel_launch(void* const* d_in, const int* in_sizes, int n_in,
                              void* d_out, int out_size, void* d_ws, size_t ws_size,
                              hipStream_t stream) {
    const float* x    = (const float*)d_in[0];
    const int*   ei   = (const int*)d_in[1];
    const float* W    = (const float*)d_in[2];
    const float* b    = (const float*)d_in[3];
    const float* W_sl = (const float*)d_in[4];
    const float* b_sl = (const float*)d_in[5];
    float* out = (float*)d_out;

    // workspace layout (~39 MB, all 16B-aligned)
    int*    cnt      = (int*)d_ws;                       // 400000
    int*    off      = cnt + N_CNT;                      // 400000
    int*    cur      = off + N_CNT;                      // 400000
    int*    partials = cur + N_CNT;                      // 512
    float*  Bmat     = (float*)(partials + 512);         // 640*128
    ushort* xbf      = (ushort*)(Bmat + 640 * 128);      // 12.8M ushorts
    int*    sorted   = (int*)(xbf + (size_t)N_NODES * D);// 2M ints

    hipMemsetAsync(cnt, 0, N_CNT * sizeof(int), stream);

    cvt_kernel<<<((N_NODES * D / 4) + 255) / 256, 256, 0, stream>>>(x, xbf);
    build_bmat<<<(640 * 128 + 255) / 256, 256, 0, stream>>>(W, W_sl, Bmat);

    int ethreads = N_REL * N_EDGES;                 // 2,000,000
    int eblocks = (ethreads + 255) / 256;           // 7813
    hist_kernel<<<eblocks, 256, 0, stream>>>(ei, cnt);
    scanA<<<N_SCAN_BLK, 256, 0, stream>>>(cnt, off, partials);
    scanB<<<1, 512, 0, stream>>>(partials);
    scanC<<<(N_CNT + 255) / 256, 256, 0, stream>>>(off, cur, partials);
    bucket_kernel<<<eblocks, 256, 0, stream>>>(ei, cur, sorted);

    fused_kernel<<<N_BLK, 256, 0, stream>>>(x, xbf, sorted, off, cnt, Bmat, b, b_sl, out);
}

// Round 4
// 439.748 us; speedup vs baseline: 8.6644x; 1.8569x over previous
//
#include <hip/hip_runtime.h>
#include <hip/hip_bf16.h>

#define N_NODES 100000
#define D 128
#define N_REL 4
#define N_EDGES 500000
#define N_CNT (N_REL * N_NODES)                                  // 400,000
#define SCAN_CHUNK 1024
#define N_SCAN_BLK ((N_CNT + SCAN_CHUNK - 1) / SCAN_CHUNK)       // 391

typedef __attribute__((ext_vector_type(8))) short bf16x8;
typedef __attribute__((ext_vector_type(4))) float f32x4;

__device__ __forceinline__ unsigned short f2bf(float f) {
    unsigned int u = __float_as_uint(f);
    u += 0x7fffu + ((u >> 16) & 1u);
    return (unsigned short)(u >> 16);
}

// ---------------- prep: fused x->bf16 cvt | W^T build (bf16) | per-(rel,tgt) histogram
#define CVT_BLOCKS 6250    // 8 floats/thread * 256 = 2048 floats/blk; 12.8M/2048
#define WB_BLOCKS 320      // 81920 elems / 256
#define HIST_BLOCKS 7813   // 2,000,128 threads >= 2M edges
__global__ __launch_bounds__(256) void prep_kernel(const float* __restrict__ x,
                                                   const int* __restrict__ ei,
                                                   const float* __restrict__ W,
                                                   const float* __restrict__ W_sl,
                                                   ushort* __restrict__ xbf,
                                                   ushort* __restrict__ WbT,
                                                   int* __restrict__ cnt) {
    const int b = blockIdx.x, tid = threadIdx.x;
    if (b < CVT_BLOCKS) {
        size_t t = (size_t)b * 256 + tid;                 // one int4 (8 bf16) per thread
        float4 v0 = ((const float4*)x)[t * 2];
        float4 v1 = ((const float4*)x)[t * 2 + 1];
        int4 o;
        o.x = ((int)f2bf(v0.y) << 16) | f2bf(v0.x);
        o.y = ((int)f2bf(v0.w) << 16) | f2bf(v0.z);
        o.z = ((int)f2bf(v1.y) << 16) | f2bf(v1.x);
        o.w = ((int)f2bf(v1.w) << 16) | f2bf(v1.z);
        ((int4*)xbf)[t] = o;
    } else if (b < CVT_BLOCKS + WB_BLOCKS) {
        // WbT[f][k], k = r*128+d (k<512) -> W[r][f][d]; k in [512,640) -> W_sl[f][k-512]
        int t = (b - CVT_BLOCKS) * 256 + tid;             // 0..81919
        int f = t / 640;
        int k = t - f * 640;
        float v;
        if (k < 512) {
            int r = k >> 7, d = k & 127;
            v = W[((size_t)r * 128 + f) * 128 + d];
        } else {
            v = W_sl[(size_t)f * 128 + (k - 512)];
        }
        WbT[t] = f2bf(v);
    } else {
        int t = (b - CVT_BLOCKS - WB_BLOCKS) * 256 + tid;
        if (t >= N_REL * N_EDGES) return;
        int r = t / N_EDGES;
        int e = t - r * N_EDGES;
        int tgt = ei[(size_t)r * 2 * N_EDGES + N_EDGES + e];
        atomicAdd(&cnt[r * N_NODES + tgt], 1);
    }
}

// ---------------- scan (chunk-local prefix + block partials; consumers add partials)
__global__ __launch_bounds__(256) void scanA(const int* __restrict__ cnt,
                                             int* __restrict__ off,
                                             int* __restrict__ partials) {
    __shared__ int ps[256];
    int b = blockIdx.x, t = threadIdx.x;
    int i0 = b * SCAN_CHUNK + t * 4;
    int v[4];
#pragma unroll
    for (int q = 0; q < 4; ++q) v[q] = (i0 + q < N_CNT) ? cnt[i0 + q] : 0;
    int s = v[0] + v[1] + v[2] + v[3];
    ps[t] = s;
    __syncthreads();
    for (int d = 1; d < 256; d <<= 1) {
        int u = (t >= d) ? ps[t - d] : 0;
        __syncthreads();
        ps[t] += u;
        __syncthreads();
    }
    if (t == 255) partials[b] = ps[255];
    int run = (t == 0) ? 0 : ps[t - 1];
#pragma unroll
    for (int q = 0; q < 4; ++q) {
        if (i0 + q < N_CNT) off[i0 + q] = run;
        run += v[q];
    }
}
__global__ __launch_bounds__(512) void scanB(int* __restrict__ partials) {
    __shared__ int ps[512];
    int t = threadIdx.x;
    ps[t] = (t < N_SCAN_BLK) ? partials[t] : 0;
    __syncthreads();
    for (int d = 1; d < 512; d <<= 1) {
        int u = (t >= d) ? ps[t - d] : 0;
        __syncthreads();
        ps[t] += u;
        __syncthreads();
    }
    if (t < N_SCAN_BLK) partials[t] = (t == 0) ? 0 : ps[t - 1];
}

// ---------------- scatter src into (rel,tgt)-sorted order (cur0 pre-zeroed)
__global__ __launch_bounds__(256) void bucket_kernel(const int* __restrict__ ei,
                                                     const int* __restrict__ off,
                                                     const int* __restrict__ partials,
                                                     int* __restrict__ cur0,
                                                     int* __restrict__ sorted) {
    int t = blockIdx.x * 256 + threadIdx.x;
    if (t >= N_REL * N_EDGES) return;
    int r = t / N_EDGES;
    int e = t - r * N_EDGES;
    int src = ei[(size_t)r * 2 * N_EDGES + e];
    int tgt = ei[(size_t)r * 2 * N_EDGES + N_EDGES + e];
    int i = r * N_NODES + tgt;
    int pos = off[i] + partials[i >> 10] + atomicAdd(&cur0[i], 1);
    sorted[pos] = src;
}

// ---------------- gather: one wave per (rel,node); bf16 agg row out (always written)
__global__ __launch_bounds__(512) void gather_kernel(const ushort* __restrict__ xbf,
                                                     const int* __restrict__ sorted,
                                                     const int* __restrict__ off,
                                                     const int* __restrict__ partials,
                                                     const int* __restrict__ cnt,
                                                     unsigned int* __restrict__ buf) {
    const int p = blockIdx.x * 8 + (threadIdx.x >> 6);   // 0..399999
    const int lane = threadIdx.x & 63;
    int base = __builtin_amdgcn_readfirstlane(off[p] + partials[p >> 10]);
    int c = __builtin_amdgcn_readfirstlane(cnt[p]);
    float ax = 0.f, ay = 0.f;
    int j = 0;
    for (; j + 4 <= c; j += 4) {
        int s0 = sorted[base + j + 0];
        int s1 = sorted[base + j + 1];
        int s2 = sorted[base + j + 2];
        int s3 = sorted[base + j + 3];
        unsigned int u0 = ((const unsigned int*)(xbf + ((size_t)s0 << 7)))[lane];
        unsigned int u1 = ((const unsigned int*)(xbf + ((size_t)s1 << 7)))[lane];
        unsigned int u2 = ((const unsigned int*)(xbf + ((size_t)s2 << 7)))[lane];
        unsigned int u3 = ((const unsigned int*)(xbf + ((size_t)s3 << 7)))[lane];
        ax += __uint_as_float(u0 << 16) + __uint_as_float(u1 << 16)
            + __uint_as_float(u2 << 16) + __uint_as_float(u3 << 16);
        ay += __uint_as_float(u0 & 0xffff0000u) + __uint_as_float(u1 & 0xffff0000u)
            + __uint_as_float(u2 & 0xffff0000u) + __uint_as_float(u3 & 0xffff0000u);
    }
    for (; j < c; ++j) {
        int s0 = sorted[base + j];
        unsigned int u0 = ((const unsigned int*)(xbf + ((size_t)s0 << 7)))[lane];
        ax += __uint_as_float(u0 << 16);
        ay += __uint_as_float(u0 & 0xffff0000u);
    }
    buf[(size_t)p * 64 + lane] = ((unsigned int)f2bf(ay) << 16) | f2bf(ax);
}

// ---------------- MFMA GEMM: out[100000][128] = A[100000][640]bf16 @ B[640][128]bf16 + bias
// A cols: [r*128+d] -> buf agg; [512..640) -> xbf. 128x128 tile, 4 waves (2x2), 16x16x32 mfma.
__global__ __launch_bounds__(256) void gemm_kernel(const ushort* __restrict__ buf,
                                                   const ushort* __restrict__ xbf,
                                                   const ushort* __restrict__ WbT,
                                                   const int* __restrict__ cnt,
                                                   const float* __restrict__ bias,
                                                   const float* __restrict__ b_sl,
                                                   float* __restrict__ out) {
    __shared__ __align__(16) ushort As[128 * 72];   // [row][k] pad 64->72 (16B-aligned rows)
    __shared__ __align__(16) ushort Bs[128 * 72];   // [f][k]
    __shared__ float degS[4 * 128];
    __shared__ float biasS[4 * 128];
    __shared__ float bslS[128];

    const int tid = threadIdx.x;
    const int l = tid & 63, w = tid >> 6;
    const int wr = w >> 1, wc = w & 1;
    const int lr = l & 15, lq = l >> 4;
    const int n0 = blockIdx.x * 128;

#pragma unroll
    for (int it = 0; it < 2; ++it) {
        int idx = it * 256 + tid;
        int r = idx >> 7, row = idx & 127;
        int n = n0 + row;
        degS[idx] = (n < N_NODES) ? (float)cnt[r * N_NODES + n] : 0.f;
        biasS[idx] = bias[idx];
    }
    if (tid < 128) bslS[tid] = b_sl[tid];

    f32x4 acc[4][4];
#pragma unroll
    for (int mi = 0; mi < 4; ++mi)
#pragma unroll
        for (int ni = 0; ni < 4; ++ni) acc[mi][ni] = (f32x4){0.f, 0.f, 0.f, 0.f};

    for (int kt = 0; kt < 10; ++kt) {
        __syncthreads();   // also covers deg/bias staging on kt==0
        const int region = kt >> 1;
        const int d0 = (kt & 1) * 64;
        // stage A tile: 128 rows x 64 bf16 (8 x 16B chunks per row)
#pragma unroll
        for (int it = 0; it < 4; ++it) {
            int id = it * 256 + tid;
            int r_ = id >> 3, c16 = id & 7;
            int n = n0 + r_;
            if (n > N_NODES - 1) n = N_NODES - 1;   // clamp: keeps loads in-bounds
            const ushort* sp = (region < 4)
                ? ((const ushort*)buf + (((size_t)region * N_NODES + n) << 7) + d0)
                : (xbf + ((size_t)n << 7) + d0);
            int4 v = *(const int4*)(sp + c16 * 8);
            *(int4*)(As + r_ * 72 + c16 * 8) = v;
        }
        // stage B tile: 128 f x 64 k from WbT[f][640]
#pragma unroll
        for (int it = 0; it < 4; ++it) {
            int id = it * 256 + tid;
            int f_ = id >> 3, c16 = id & 7;
            int4 v = *(const int4*)(WbT + (size_t)f_ * 640 + kt * 64 + c16 * 8);
            *(int4*)(Bs + f_ * 72 + c16 * 8) = v;
        }
        __syncthreads();
#pragma unroll
        for (int ks = 0; ks < 2; ++ks) {
            bf16x8 a[4], bb[4];
#pragma unroll
            for (int mi = 0; mi < 4; ++mi)
                a[mi] = *(const bf16x8*)(As + (wr * 64 + mi * 16 + lr) * 72 + ks * 32 + lq * 8);
#pragma unroll
            for (int ni = 0; ni < 4; ++ni)
                bb[ni] = *(const bf16x8*)(Bs + (wc * 64 + ni * 16 + lr) * 72 + ks * 32 + lq * 8);
#pragma unroll
            for (int mi = 0; mi < 4; ++mi)
#pragma unroll
                for (int ni = 0; ni < 4; ++ni)
                    acc[mi][ni] = __builtin_amdgcn_mfma_f32_16x16x32_bf16(a[mi], bb[ni], acc[mi][ni], 0, 0, 0);
        }
    }

    // epilogue: C/D frag layout col=lane&15, row=(lane>>4)*4+q (m89-verified)
    float bw[4][4], bsl_[4];   // [ni][r]
#pragma unroll
    for (int ni = 0; ni < 4; ++ni) {
        int f = wc * 64 + ni * 16 + lr;
        bsl_[ni] = bslS[f];
#pragma unroll
        for (int r = 0; r < 4; ++r) bw[ni][r] = biasS[r * 128 + f];
    }
#pragma unroll
    for (int mi = 0; mi < 4; ++mi) {
#pragma unroll
        for (int q = 0; q < 4; ++q) {
            int row = wr * 64 + mi * 16 + lq * 4 + q;
            int n = n0 + row;
            if (n >= N_NODES) continue;
            float d0_ = degS[row], d1_ = degS[128 + row], d2_ = degS[256 + row], d3_ = degS[384 + row];
#pragma unroll
            for (int ni = 0; ni < 4; ++ni) {
                int f = wc * 64 + ni * 16 + lr;
                float v = acc[mi][ni][q] + d0_ * bw[ni][0] + d1_ * bw[ni][1]
                        + d2_ * bw[ni][2] + d3_ * bw[ni][3] + bsl_[ni];
                out[(size_t)n * 128 + f] = v;
            }
        }
    }
}

extern "C" void kernel_launch(void* const* d_in, const int* in_sizes, int n_in,
                              void* d_out, int out_size, void* d_ws, size_t ws_size,
                              hipStream_t stream) {
    const float* x    = (const float*)d_in[0];
    const int*   ei   = (const int*)d_in[1];
    const float* W    = (const float*)d_in[2];
    const float* b    = (const float*)d_in[3];
    const float* W_sl = (const float*)d_in[4];
    const float* b_sl = (const float*)d_in[5];
    float* out = (float*)d_out;

    // ws layout (~143 MB), all 256B-aligned
    int*          cnt      = (int*)d_ws;                          // 400000
    int*          cur0     = cnt + N_CNT;                         // 400000 (adjacent: one memset)
    int*          off      = cur0 + N_CNT;                        // 400000
    int*          partials = off + N_CNT;                         // 512
    ushort*       WbT      = (ushort*)(partials + 512);           // 128*640
    ushort*       xbf      = WbT + 128 * 640;                     // 12.8M
    int*          sorted   = (int*)(xbf + (size_t)N_NODES * D);   // 2M
    unsigned int* buf      = (unsigned int*)(sorted + N_REL * N_EDGES);  // 400000*64 uints

    hipMemsetAsync(cnt, 0, 2 * N_CNT * sizeof(int), stream);      // cnt + cur0

    prep_kernel<<<CVT_BLOCKS + WB_BLOCKS + HIST_BLOCKS, 256, 0, stream>>>(x, ei, W, W_sl, xbf, WbT, cnt);
    scanA<<<N_SCAN_BLK, 256, 0, stream>>>(cnt, off, partials);
    scanB<<<1, 512, 0, stream>>>(partials);
    bucket_kernel<<<(N_REL * N_EDGES + 255) / 256, 256, 0, stream>>>(ei, off, partials, cur0, sorted);
    gather_kernel<<<N_CNT / 8, 512, 0, stream>>>(xbf, sorted, off, partials, cnt, buf);
    gemm_kernel<<<(N_NODES + 127) / 128, 256, 0, stream>>>((const ushort*)buf, xbf, WbT, cnt, b, b_sl, out);
}